// Round 1
// baseline (232.560 us; speedup 1.0000x reference)
//
#include <hip/hip_runtime.h>
#include <hip/hip_bf16.h>

#define DIM    286
#define DIMP   288
#define NZTOT  55296     // 48*24*48
#define NBATCH 256
#define NB_    24
#define NA_    48
#define ZC     32        // z per tile
#define NTILES 1728      // NZTOT/ZC
#define NCHUNK 192       // z-chunk workgroups (grid.x)
#define TILES_PER_WG 9   // NTILES/NCHUNK
#define S_CONST 16.911534525287763f
#define INV_S   0.05913123959890826f

typedef short bf16x8 __attribute__((ext_vector_type(8)));
typedef float f32x4  __attribute__((ext_vector_type(4)));

// ws layout (bytes), all 256-aligned
#define WS_FBF  0u
#define WS_DBF  147456u                      // Fbf: 256*288*2
#define WS_DT   (WS_DBF + 31850496u)         // Dbf: 55296*288*2
#define WS_PART (WS_DT + 31850496u)          // Dt:  288*55296*2
#define WS_SUM  (WS_PART + 56623104u)        // part: 192*256*288*4

// ---------- prep: F -> bf16 [256][288], scaled by 1/s; also zero the sum slot
__global__ void k_prep_f(const float* __restrict__ F, __hip_bfloat16* __restrict__ Fbf,
                         float* __restrict__ sumslot) {
    int o = blockIdx.x * 256 + threadIdx.x;   // grid 288*256 == 73728 exactly
    if (o == 0) *sumslot = 0.f;
    int row = o / DIMP, col = o % DIMP;
    float v = (col < DIM) ? F[row * DIM + col] * INV_S : 0.f;
    Fbf[o] = __float2bfloat16(v);
}

// ---------- prep: D -> Dbf[z][288] bf16 (zero-padded) and Dt[i][z] bf16 with qw*s folded
__global__ void k_prep_d(const float* __restrict__ D, const float* __restrict__ qw,
                         __hip_bfloat16* __restrict__ Dbf, __hip_bfloat16* __restrict__ Dt) {
    __shared__ float T[64][293];             // padded: 293%32==5 -> conflict-light transpose reads
    int t = threadIdx.x;
    int z0 = blockIdx.x * 64;
    // phase 1: coalesced float4 over this block's 64 rows (64*286 = 18304 floats = 4576 float4)
    const float4* Df = (const float4*)(D + (size_t)z0 * DIM);
    for (int k = 0; k < 18; ++k) {
        int idx = t + k * 256;
        if (idx < 4576) {
            float4 v = Df[idx];
            int e = idx * 4;
            #pragma unroll
            for (int j = 0; j < 4; ++j) {
                int ee = e + j;
                int z = ee / DIM, i = ee % DIM;
                float val = ((const float*)&v)[j];
                T[z][i] = val;
                Dbf[(size_t)(z0 + z) * DIMP + i] = __float2bfloat16(val);
            }
        }
    }
    if (t < 128) {  // zero K-padding cols 286..287
        int z = t >> 1, i = DIM + (t & 1);
        T[z][i] = 0.f;
        Dbf[(size_t)(z0 + z) * DIMP + i] = __float2bfloat16(0.f);
    }
    __syncthreads();
    // phase 2: Dt[i][z0+z] = T[z][i] * qw[y]*s ; wave = one i-row, coalesced global writes
    for (int m = 0; m < 72; ++m) {
        int flat = t + m * 256;              // over [288][64]
        int i = flat >> 6, z = flat & 63;
        int y = ((z0 + z) / NA_) % NB_;
        float val = T[z][i] * qw[y] * S_CONST;
        Dt[(size_t)i * NZTOT + z0 + z] = __float2bfloat16(val);
    }
}

// ---------- ACT_CST integral: sum tanh(x)^2 * exp(-x^2/2) over reference's trapz grid
__global__ void k_integral(float* __restrict__ sumslot) {
    int idx = blockIdx.x * 256 + threadIdx.x;   // 16*256 = 4096 threads
    float p = 0.f;
    for (int i = idx; i < 1000001; i += 4096) {
        float x = -12.f + (float)i * 2.4e-5f;
        float th = tanhf(x);
        p += th * th * __expf(-0.5f * x * x);
    }
    #pragma unroll
    for (int off = 32; off > 0; off >>= 1) p += __shfl_down(p, off);
    __shared__ float wsum[4];
    if ((threadIdx.x & 63) == 0) wsum[threadIdx.x >> 6] = p;
    __syncthreads();
    if (threadIdx.x == 0) atomicAdd(sumslot, wsum[0] + wsum[1] + wsum[2] + wsum[3]);
}

// ---------- fused main: per 32-z tile: G = F*D^T (bf16 MFMA), tanh, Out += G_act * (qw*s*D)
__launch_bounds__(256, 3)
__global__ void k_main(const __hip_bfloat16* __restrict__ Fbf,
                       const __hip_bfloat16* __restrict__ Dbf,
                       const __hip_bfloat16* __restrict__ Dt,
                       const float* __restrict__ sumslot,
                       float* __restrict__ part) {
    __shared__ __align__(16) __hip_bfloat16 Ds[32][296];    // [z][i] pad: 148w%32=20
    __shared__ __align__(16) __hip_bfloat16 Dts[288][40];   // [i][z] pad: 20w%32=20
    __shared__ __align__(16) __hip_bfloat16 Gs[4][16][40];  // per-wave act relayout

    int t = threadIdx.x;
    int wave = t >> 6, lane = t & 63, ln = lane & 15, q = lane >> 4;
    float act_cst = rsqrtf((*sumslot) * (2.4e-5f * 0.3989422804014327f));

    // cache F A-frags for this wave's 16 batch rows (9 K-steps of 32)
    bf16x8 fa[9];
    int row = blockIdx.y * 64 + wave * 16 + ln;
    const __hip_bfloat16* fp = Fbf + (size_t)row * DIMP + q * 8;
    #pragma unroll
    for (int ks = 0; ks < 9; ++ks) fa[ks] = *(const bf16x8*)(fp + ks * 32);

    f32x4 acc[18];
    #pragma unroll
    for (int n = 0; n < 18; ++n) acc[n] = (f32x4){0.f, 0.f, 0.f, 0.f};

    #pragma unroll 1
    for (int k = 0; k < TILES_PER_WG; ++k) {
        int tz = blockIdx.x + k * NCHUNK;
        size_t zbase = (size_t)tz * ZC;
        // stage Ds: 32 rows * 36 chunks of 16B, coalesced
        {
            const bf16x8* src = (const bf16x8*)(Dbf + zbase * DIMP);
            for (int s = 0; s < 5; ++s) {
                int idx = t + s * 256;
                if (idx < 1152) {
                    int r = idx / 36, c = idx % 36;
                    *(bf16x8*)(&Ds[r][c * 8]) = src[r * 36 + c];
                }
            }
            // stage Dts: 288 rows * 4 chunks of 16B
            for (int s = 0; s < 5; ++s) {
                int idx = t + s * 256;
                if (idx < 1152) {
                    int ir = idx >> 2, zc = idx & 3;
                    *(bf16x8*)(&Dts[ir][zc * 8]) =
                        *(const bf16x8*)(Dt + (size_t)ir * NZTOT + zbase + zc * 8);
                }
            }
        }
        __syncthreads();
        // GEMM1: G[16 x 32] per wave, K=288
        f32x4 g0 = (f32x4){0.f,0.f,0.f,0.f}, g1 = (f32x4){0.f,0.f,0.f,0.f};
        #pragma unroll
        for (int ks = 0; ks < 9; ++ks) {
            bf16x8 b0 = *(const bf16x8*)(&Ds[ln][ks * 32 + q * 8]);
            bf16x8 b1 = *(const bf16x8*)(&Ds[16 + ln][ks * 32 + q * 8]);
            g0 = __builtin_amdgcn_mfma_f32_16x16x32_bf16(fa[ks], b0, g0, 0, 0, 0);
            g1 = __builtin_amdgcn_mfma_f32_16x16x32_bf16(fa[ks], b1, g1, 0, 0, 0);
        }
        // act = ACT_CST * tanh(g); relayout C-layout -> A-layout via per-wave LDS
        #pragma unroll
        for (int nf = 0; nf < 2; ++nf) {
            #pragma unroll
            for (int r = 0; r < 4; ++r) {
                float x = (nf == 0) ? g0[r] : g1[r];
                float a = fabsf(x);
                float e = __expf(-2.f * a);
                float th = (1.f - e) / (1.f + e);
                float v = copysignf(act_cst * th, x);
                Gs[wave][q * 4 + r][nf * 16 + ln] = __float2bfloat16(v);
            }
        }
        // GEMM2: Out[16 x 288] += G_act[16 x 32] * Dts (own-wave Gs only: no barrier needed)
        bf16x8 a2 = *(const bf16x8*)(&Gs[wave][ln][q * 8]);
        #pragma unroll
        for (int nf = 0; nf < 18; ++nf) {
            bf16x8 b2 = *(const bf16x8*)(&Dts[nf * 16 + ln][q * 8]);
            acc[nf] = __builtin_amdgcn_mfma_f32_16x16x32_bf16(a2, b2, acc[nf], 0, 0, 0);
        }
        __syncthreads();   // protect Ds/Dts before next stage
    }
    // epilogue: partial[zc][batch][288]
    float* pb = part + ((size_t)blockIdx.x * NBATCH + blockIdx.y * 64 + wave * 16) * DIMP;
    #pragma unroll
    for (int nf = 0; nf < 18; ++nf) {
        #pragma unroll
        for (int r = 0; r < 4; ++r) {
            pb[(size_t)(q * 4 + r) * DIMP + nf * 16 + ln] = acc[nf][r];
        }
    }
}

// ---------- reduce partials over the 192 z-chunks
__global__ void k_reduce(const float* __restrict__ part, float* __restrict__ out) {
    int o = blockIdx.x * 256 + threadIdx.x;
    if (o >= NBATCH * DIM) return;
    int b = o / DIM, i = o % DIM;
    const float* p = part + (size_t)b * DIMP + i;
    float s = 0.f;
    #pragma unroll 4
    for (int zc = 0; zc < NCHUNK; ++zc) s += p[(size_t)zc * NBATCH * DIMP];
    out[o] = s;
}

extern "C" void kernel_launch(void* const* d_in, const int* in_sizes, int n_in,
                              void* d_out, int out_size, void* d_ws, size_t ws_size,
                              hipStream_t stream) {
    const float* F  = (const float*)d_in[0];
    const float* D  = (const float*)d_in[1];
    const float* qw = (const float*)d_in[2];
    char* ws = (char*)d_ws;
    __hip_bfloat16* Fbf = (__hip_bfloat16*)(ws + WS_FBF);
    __hip_bfloat16* Dbf = (__hip_bfloat16*)(ws + WS_DBF);
    __hip_bfloat16* Dt  = (__hip_bfloat16*)(ws + WS_DT);
    float* part = (float*)(ws + WS_PART);
    float* sums = (float*)(ws + WS_SUM);

    k_prep_f<<<288, 256, 0, stream>>>(F, Fbf, sums);
    k_prep_d<<<864, 256, 0, stream>>>(D, qw, Dbf, Dt);
    k_integral<<<16, 256, 0, stream>>>(sums);
    k_main<<<dim3(NCHUNK, 4), 256, 0, stream>>>(Fbf, Dbf, Dt, sums, part);
    k_reduce<<<286, 256, 0, stream>>>(part, (float*)d_out);
}

// Round 2
// 188.009 us; speedup vs baseline: 1.2370x; 1.2370x over previous
//
#include <hip/hip_runtime.h>
#include <hip/hip_bf16.h>

#define DIM    286
#define DIMP   288
#define NZTOT  55296     // 48*24*48
#define NBATCH 256
#define NB_    24
#define NA_    48
#define ZC     32        // z per tile
#define NTILES 1728      // NZTOT/ZC
#define NCHUNK 192       // z-chunk workgroups (grid.x)
#define TILES_PER_WG 9   // NTILES/NCHUNK
#define S_CONST 16.911534525287763f
#define INV_S   0.05913123959890826f

typedef short bf16x8 __attribute__((ext_vector_type(8)));
typedef float f32x4  __attribute__((ext_vector_type(4)));

// ws layout (bytes), all 16-aligned
#define WS_FBF  0u
#define WS_DBF  147456u                      // Fbf: 256*288*2
#define WS_DT   (WS_DBF + 31850496u)         // Dbf: 55296*288*2
#define WS_PART (WS_DT + 31850496u)          // Dt2: 1728 tiles * 288 * 32 * 2
#define WS_SUM  (WS_PART + 56623104u)        // part: 192*256*288*4

// ---------- prep: F -> bf16 [256][288], scaled by 1/s; also zero the sum slot
__global__ void k_prep_f(const float* __restrict__ F, __hip_bfloat16* __restrict__ Fbf,
                         float* __restrict__ sumslot) {
    int o = blockIdx.x * 256 + threadIdx.x;   // grid 288*256 == 73728 exactly
    if (o == 0) *sumslot = 0.f;
    int row = o / DIMP, col = o % DIMP;
    float v = (col < DIM) ? F[row * DIM + col] * INV_S : 0.f;
    Fbf[o] = __float2bfloat16(v);
}

// ---------- prep: D -> Dbf[z][288] bf16 (zero-padded) and Dt2[tile][i][32] bf16 w/ qw*s
__global__ void k_prep_d(const float* __restrict__ D, const float* __restrict__ qw,
                         __hip_bfloat16* __restrict__ Dbf, __hip_bfloat16* __restrict__ Dt2) {
    __shared__ float T[64][300];             // 300%32=12: row bank offset 12
    __shared__ float qs[24];
    int t = threadIdx.x;
    int z0 = blockIdx.x * 64;
    if (t < 24) qs[t] = qw[t] * S_CONST;
    // phase 1: coalesced float4 loads of 64 rows (64*286 = 18304 floats = 4576 float4)
    const float4* Df = (const float4*)(D + (size_t)z0 * DIM);
    for (int k = 0; k < 18; ++k) {
        int idx = t + k * 256;
        if (idx < 4576) {
            float4 v = Df[idx];
            int e = idx * 4;
            #pragma unroll
            for (int j = 0; j < 4; ++j) {
                int ee = e + j;
                int z = ee / DIM, i = ee % DIM;
                T[z][i] = ((const float*)&v)[j];
            }
        }
    }
    if (t < 128) {  // zero K-padding cols 286..287
        int z = t >> 1, i = DIM + (t & 1);
        T[z][i] = 0.f;
    }
    __syncthreads();
    // phase 2: Dbf coalesced bf16x8 writes: 64 rows * 36 chunks
    for (int s = 0; s < 9; ++s) {
        int idx = t + s * 256;               // 2304 chunks
        int r = idx / 36, c = idx % 36;
        float4 a = *(const float4*)(&T[r][c * 8]);
        float4 b = *(const float4*)(&T[r][c * 8 + 4]);
        __hip_bfloat16 o8[8];
        o8[0] = __float2bfloat16(a.x); o8[1] = __float2bfloat16(a.y);
        o8[2] = __float2bfloat16(a.z); o8[3] = __float2bfloat16(a.w);
        o8[4] = __float2bfloat16(b.x); o8[5] = __float2bfloat16(b.y);
        o8[6] = __float2bfloat16(b.z); o8[7] = __float2bfloat16(b.w);
        *(bf16x8*)(Dbf + (size_t)(z0 + r) * DIMP + c * 8) = *(const bf16x8*)o8;
    }
    // phase 3: Dt2[tzg][i][z_in_tile] = T[z][i]*qw[y]*s, fully coalesced 16B/lane writes
    for (int s = 0; s < 9; ++s) {
        int idx = t + s * 256;               // 2304 = 2 tz * 288 i * 4 zgroups
        int tz = idx / 1152, rem = idx % 1152;
        int i = rem >> 2, zc = rem & 3;
        __hip_bfloat16 o8[8];
        #pragma unroll
        for (int j = 0; j < 8; ++j) {
            int jj = (j + 2 * zc) & 7;       // bank-conflict rotation
            int zl = tz * 32 + zc * 8 + jj;
            int y = ((z0 + zl) / NA_) % NB_;
            o8[jj] = __float2bfloat16(T[zl][i] * qs[y]);
        }
        int tzg = blockIdx.x * 2 + tz;
        *(bf16x8*)(Dt2 + ((size_t)tzg * DIMP + i) * ZC + zc * 8) = *(const bf16x8*)o8;
    }
}

// ---------- ACT_CST integral: sum tanh(x)^2 * exp(-x^2/2) over reference's trapz grid
__global__ void k_integral(float* __restrict__ sumslot) {
    int idx = blockIdx.x * 256 + threadIdx.x;   // 64*256 = 16384 threads
    float p = 0.f;
    for (int i = idx; i < 1000001; i += 16384) {
        float x = -12.f + (float)i * 2.4e-5f;
        float th = tanhf(x);
        p += th * th * __expf(-0.5f * x * x);
    }
    #pragma unroll
    for (int off = 32; off > 0; off >>= 1) p += __shfl_down(p, off);
    __shared__ float wsum[4];
    if ((threadIdx.x & 63) == 0) wsum[threadIdx.x >> 6] = p;
    __syncthreads();
    if (threadIdx.x == 0) atomicAdd(sumslot, wsum[0] + wsum[1] + wsum[2] + wsum[3]);
}

// ---------- fused main: per 32-z tile: G = F*D^T (bf16 MFMA), tanh, Out += G_act * (qw*s*D)
__launch_bounds__(256, 3)
__global__ void k_main(const __hip_bfloat16* __restrict__ Fbf,
                       const __hip_bfloat16* __restrict__ Dbf,
                       const __hip_bfloat16* __restrict__ Dt2,
                       const float* __restrict__ sumslot,
                       float* __restrict__ part) {
    __shared__ __align__(16) __hip_bfloat16 Ds[32][296];    // [z][i]
    __shared__ __align__(16) __hip_bfloat16 Dts[288][40];   // [i][z]
    __shared__ __align__(16) __hip_bfloat16 Gs[4][16][40];  // per-wave act relayout

    int t = threadIdx.x;
    int wave = t >> 6, lane = t & 63, ln = lane & 15, q = lane >> 4;
    float act_cst = rsqrtf((*sumslot) * (2.4e-5f * 0.3989422804014327f));

    // cache F A-frags for this wave's 16 batch rows (9 K-steps of 32)
    bf16x8 fa[9];
    int row = blockIdx.y * 64 + wave * 16 + ln;
    const __hip_bfloat16* fp = Fbf + (size_t)row * DIMP + q * 8;
    #pragma unroll
    for (int ks = 0; ks < 9; ++ks) fa[ks] = *(const bf16x8*)(fp + ks * 32);

    f32x4 acc[18];
    #pragma unroll
    for (int n = 0; n < 18; ++n) acc[n] = (f32x4){0.f, 0.f, 0.f, 0.f};

    #pragma unroll 1
    for (int k = 0; k < TILES_PER_WG; ++k) {
        int tz = blockIdx.x + k * NCHUNK;
        size_t zbase = (size_t)tz * ZC;
        // stage Ds: 32 rows * 36 chunks of 16B, contiguous source
        {
            const bf16x8* src = (const bf16x8*)(Dbf + zbase * DIMP);
            const bf16x8* srct = (const bf16x8*)(Dt2 + (size_t)tz * DIMP * ZC);
            for (int s = 0; s < 5; ++s) {
                int idx = t + s * 256;
                if (idx < 1152) {
                    int r = idx / 36, c = idx % 36;
                    *(bf16x8*)(&Ds[r][c * 8]) = src[idx];
                    // stage Dts: contiguous tile-major source
                    int ir = idx >> 2, zc = idx & 3;
                    *(bf16x8*)(&Dts[ir][zc * 8]) = srct[idx];
                }
            }
        }
        __syncthreads();
        // GEMM1: G[16 x 32] per wave, K=288
        f32x4 g0 = (f32x4){0.f,0.f,0.f,0.f}, g1 = (f32x4){0.f,0.f,0.f,0.f};
        #pragma unroll
        for (int ks = 0; ks < 9; ++ks) {
            bf16x8 b0 = *(const bf16x8*)(&Ds[ln][ks * 32 + q * 8]);
            bf16x8 b1 = *(const bf16x8*)(&Ds[16 + ln][ks * 32 + q * 8]);
            g0 = __builtin_amdgcn_mfma_f32_16x16x32_bf16(fa[ks], b0, g0, 0, 0, 0);
            g1 = __builtin_amdgcn_mfma_f32_16x16x32_bf16(fa[ks], b1, g1, 0, 0, 0);
        }
        // act = ACT_CST * tanh(g); relayout C-layout -> A-layout via per-wave LDS
        #pragma unroll
        for (int nf = 0; nf < 2; ++nf) {
            #pragma unroll
            for (int r = 0; r < 4; ++r) {
                float x = (nf == 0) ? g0[r] : g1[r];
                float a = fabsf(x);
                float e = __expf(-2.f * a);
                float th = (1.f - e) / (1.f + e);
                float v = copysignf(act_cst * th, x);
                Gs[wave][q * 4 + r][nf * 16 + ln] = __float2bfloat16(v);
            }
        }
        // GEMM2: Out[16 x 288] += G_act[16 x 32] * Dts (own-wave Gs only: no barrier needed)
        bf16x8 a2 = *(const bf16x8*)(&Gs[wave][ln][q * 8]);
        #pragma unroll
        for (int nf = 0; nf < 18; ++nf) {
            bf16x8 b2 = *(const bf16x8*)(&Dts[nf * 16 + ln][q * 8]);
            acc[nf] = __builtin_amdgcn_mfma_f32_16x16x32_bf16(a2, b2, acc[nf], 0, 0, 0);
        }
        __syncthreads();   // protect Ds/Dts before next stage
    }
    // epilogue: partial[zc][batch][288]
    float* pb = part + ((size_t)blockIdx.x * NBATCH + blockIdx.y * 64 + wave * 16) * DIMP;
    #pragma unroll
    for (int nf = 0; nf < 18; ++nf) {
        #pragma unroll
        for (int r = 0; r < 4; ++r) {
            pb[(size_t)(q * 4 + r) * DIMP + nf * 16 + ln] = acc[nf][r];
        }
    }
}

// ---------- reduce partials over the 192 z-chunks (4 waves split the chunk range)
__global__ void k_reduce(const float* __restrict__ part, float* __restrict__ out) {
    __shared__ float4 red[3][64];
    int t = threadIdx.x, wave = t >> 6, lane = t & 63;
    int out4 = blockIdx.x * 64 + lane;       // 288 blocks * 64 = 18432 float4 slots
    int b = out4 / 72, c4 = out4 % 72;
    const float* p = part + (size_t)b * DIMP + c4 * 4;
    float4 s = make_float4(0.f, 0.f, 0.f, 0.f);
    for (int zc = wave * 48; zc < wave * 48 + 48; ++zc) {
        float4 v = *(const float4*)(p + (size_t)zc * NBATCH * DIMP);
        s.x += v.x; s.y += v.y; s.z += v.z; s.w += v.w;
    }
    if (wave > 0) red[wave - 1][lane] = s;
    __syncthreads();
    if (wave == 0) {
        #pragma unroll
        for (int w = 0; w < 3; ++w) {
            float4 v = red[w][lane];
            s.x += v.x; s.y += v.y; s.z += v.z; s.w += v.w;
        }
        int i0 = c4 * 4;
        float sv[4] = {s.x, s.y, s.z, s.w};
        #pragma unroll
        for (int kk = 0; kk < 4; ++kk)
            if (i0 + kk < DIM) out[b * DIM + i0 + kk] = sv[kk];
    }
}

extern "C" void kernel_launch(void* const* d_in, const int* in_sizes, int n_in,
                              void* d_out, int out_size, void* d_ws, size_t ws_size,
                              hipStream_t stream) {
    const float* F  = (const float*)d_in[0];
    const float* D  = (const float*)d_in[1];
    const float* qw = (const float*)d_in[2];
    char* ws = (char*)d_ws;
    __hip_bfloat16* Fbf = (__hip_bfloat16*)(ws + WS_FBF);
    __hip_bfloat16* Dbf = (__hip_bfloat16*)(ws + WS_DBF);
    __hip_bfloat16* Dt2 = (__hip_bfloat16*)(ws + WS_DT);
    float* part = (float*)(ws + WS_PART);
    float* sums = (float*)(ws + WS_SUM);

    k_prep_f<<<288, 256, 0, stream>>>(F, Fbf, sums);
    k_prep_d<<<864, 256, 0, stream>>>(D, qw, Dbf, Dt2);
    k_integral<<<64, 256, 0, stream>>>(sums);
    k_main<<<dim3(NCHUNK, 4), 256, 0, stream>>>(Fbf, Dbf, Dt2, sums, part);
    k_reduce<<<288, 256, 0, stream>>>(part, (float*)d_out);
}